// Round 1
// baseline (93.431 us; speedup 1.0000x reference)
//
#include <hip/hip_runtime.h>
#include <hip/hip_bf16.h>

// Problem constants (B=1)
#define R_   384
#define P_   (R_ * R_)      // 147456 pairs
#define NT_  4              // templates
#define CIN  128            // z channels
#define CKV  64             // t channels
#define NH   4              // heads
#define HC   256            // NH * 64

// Tiling
#define TP   64             // pairs per block
#define LDZ  136            // Zs row stride (bf16 elems), 128 + 8 pad
#define LDA  264            // As / Ts row stride (bf16 elems), 256 + 8 pad

typedef __attribute__((ext_vector_type(8))) short bf16x8;
typedef __attribute__((ext_vector_type(4))) float f32x4;

__device__ __forceinline__ ushort f2bf(float f) {
    uint32_t u = __float_as_uint(f);
    u += 0x7FFFu + ((u >> 16) & 1u);   // round-to-nearest-even
    return (ushort)(u >> 16);
}
__device__ __forceinline__ float bf2f(ushort h) {
    return __uint_as_float(((uint32_t)h) << 16);
}

// ---------------------------------------------------------------------------
// Precompute Mt[n][ci] = C^-0.5 * sum_c Wq[ci][h*64+c] * Wk[j][h*64+c]   (n = h*64+j)
//            Gt[co][n] =         sum_c Wv[j][h*64+c] * Wo[h*64+c][co]
// Stored transposed (k-dim innermost) so MFMA B-fragment loads are contiguous.
// ---------------------------------------------------------------------------
__global__ __launch_bounds__(256) void precompute_mg(
        const float* __restrict__ Wq, const float* __restrict__ Wk,
        const float* __restrict__ Wv, const float* __restrict__ Wo,
        ushort* __restrict__ Mt, ushort* __restrict__ Gt) {
    int tid = blockIdx.x * blockDim.x + threadIdx.x;
    if (tid < HC * CIN) {
        int n = tid >> 7, ci = tid & 127;      // n in [0,256), ci in [0,128)
        int h = n >> 6, j = n & 63;
        float acc = 0.f;
        for (int c = 0; c < 64; ++c)
            acc += Wq[ci * HC + h * 64 + c] * Wk[j * HC + h * 64 + c];
        Mt[n * CIN + ci] = f2bf(acc * 0.125f);  // C^-0.5 = 1/8
    } else {
        int t = tid - HC * CIN;
        int co = t >> 8, n = t & 255;          // co in [0,128), n in [0,256)
        int h = n >> 6, j = n & 63;
        float acc = 0.f;
        for (int c = 0; c < 64; ++c)
            acc += Wv[j * HC + h * 64 + c] * Wo[(h * 64 + c) * CIN + co];
        Gt[co * HC + n] = f2bf(acc);
    }
}

// ---------------------------------------------------------------------------
// Fused main kernel: per block of TP=64 pairs
//   stage Z,T -> LDS bf16 ; A = Z @ M' (MFMA) ; per-(pair,head) softmax ;
//   U = sum_k w_k t_k ; OUT = U @ G + bo (MFMA) ; store fp32.
// ---------------------------------------------------------------------------
__global__ __launch_bounds__(256) void tpa_fused(
        const float* __restrict__ z2d, const float* __restrict__ t2d,
        const ushort* __restrict__ Mt, const ushort* __restrict__ Gt,
        const float* __restrict__ bo, float* __restrict__ out) {

    __shared__ ushort s0[TP * LDA];   // Zs (stride LDZ) during GEMM1, then As/U (stride LDA)
    __shared__ ushort sT[TP * LDA];   // T tile: sT[p*LDA + k*64 + c]

    const int tid  = threadIdx.x;
    const int lane = tid & 63;
    const int wv   = tid >> 6;
    const int pg0  = blockIdx.x * TP;

    // ---- stage Z: 64 x 128 fp32 -> bf16 --------------------------------
    #pragma unroll
    for (int it = 0; it < 8; ++it) {
        int idx = (it * 256 + tid) * 4;          // float index in tile
        int p = idx >> 7, c = idx & 127;
        const float4 v = *(const float4*)(z2d + (size_t)(pg0 + p) * CIN + c);
        uint2 w;
        w.x = (uint32_t)f2bf(v.x) | ((uint32_t)f2bf(v.y) << 16);
        w.y = (uint32_t)f2bf(v.z) | ((uint32_t)f2bf(v.w) << 16);
        *(uint2*)&s0[p * LDZ + c] = w;
    }
    // ---- stage T: 4 x (64 x 64) fp32 -> bf16 ---------------------------
    #pragma unroll
    for (int k = 0; k < NT_; ++k) {
        const float* src = t2d + ((size_t)k * P_ + pg0) * CKV;
        #pragma unroll
        for (int it = 0; it < 4; ++it) {
            int idx = (it * 256 + tid) * 4;
            int p = idx >> 6, c = idx & 63;
            const float4 v = *(const float4*)(src + p * 64 + c);
            uint2 w;
            w.x = (uint32_t)f2bf(v.x) | ((uint32_t)f2bf(v.y) << 16);
            w.y = (uint32_t)f2bf(v.z) | ((uint32_t)f2bf(v.w) << 16);
            *(uint2*)&sT[p * LDA + k * 64 + c] = w;
        }
    }
    __syncthreads();

    const int lr = lane & 15;           // row-in-16 / col-in-16
    const int lk = (lane >> 4) << 3;    // k offset within 32-chunk

    // ---- GEMM1: A[64][256] = Zs[64][128] @ M'[128][256]
    //      wave wv owns cols [wv*64, wv*64+64)
    f32x4 acc1[4][4];
    #pragma unroll
    for (int mt = 0; mt < 4; ++mt)
        #pragma unroll
        for (int nt = 0; nt < 4; ++nt)
            acc1[mt][nt] = (f32x4){0.f, 0.f, 0.f, 0.f};

    #pragma unroll
    for (int kt = 0; kt < 4; ++kt) {
        bf16x8 af[4], bfr[4];
        #pragma unroll
        for (int mt = 0; mt < 4; ++mt)
            af[mt] = *(const bf16x8*)&s0[(mt * 16 + lr) * LDZ + kt * 32 + lk];
        #pragma unroll
        for (int nt = 0; nt < 4; ++nt) {
            int n = wv * 64 + nt * 16 + lr;
            bfr[nt] = *(const bf16x8*)(Mt + n * CIN + kt * 32 + lk);
        }
        #pragma unroll
        for (int mt = 0; mt < 4; ++mt)
            #pragma unroll
            for (int nt = 0; nt < 4; ++nt)
                acc1[mt][nt] = __builtin_amdgcn_mfma_f32_16x16x32_bf16(
                    af[mt], bfr[nt], acc1[mt][nt], 0, 0, 0);
    }
    __syncthreads();   // all waves done reading Zs before overlay write

    // ---- spill A accumulators to LDS as bf16 (C/D layout: col=lane&15, row=(lane>>4)*4+r)
    #pragma unroll
    for (int mt = 0; mt < 4; ++mt) {
        int row = mt * 16 + ((lane >> 4) << 2);
        #pragma unroll
        for (int nt = 0; nt < 4; ++nt) {
            int n = wv * 64 + nt * 16 + lr;
            #pragma unroll
            for (int r = 0; r < 4; ++r)
                s0[(row + r) * LDA + n] = f2bf(acc1[mt][nt][r]);
        }
    }
    __syncthreads();

    // ---- middle: thread (p = tid&63, h = tid>>6): logits, softmax, U ----
    {
        const int p = tid & 63, h = tid >> 6;
        const ushort* arow = &s0[p * LDA + h * 64];
        const ushort* trow = &sT[p * LDA];
        float lg0 = 0.f, lg1 = 0.f, lg2 = 0.f, lg3 = 0.f;
        #pragma unroll
        for (int c8 = 0; c8 < 8; ++c8) {
            bf16x8 av = *(const bf16x8*)&arow[c8 * 8];
            bf16x8 t0 = *(const bf16x8*)&trow[c8 * 8];
            bf16x8 t1 = *(const bf16x8*)&trow[64 + c8 * 8];
            bf16x8 t2 = *(const bf16x8*)&trow[128 + c8 * 8];
            bf16x8 t3 = *(const bf16x8*)&trow[192 + c8 * 8];
            #pragma unroll
            for (int e = 0; e < 8; ++e) {
                float a = bf2f((ushort)av[e]);
                lg0 = fmaf(a, bf2f((ushort)t0[e]), lg0);
                lg1 = fmaf(a, bf2f((ushort)t1[e]), lg1);
                lg2 = fmaf(a, bf2f((ushort)t2[e]), lg2);
                lg3 = fmaf(a, bf2f((ushort)t3[e]), lg3);
            }
        }
        float mx = fmaxf(fmaxf(lg0, lg1), fmaxf(lg2, lg3));
        float w0 = __expf(lg0 - mx), w1 = __expf(lg1 - mx);
        float w2 = __expf(lg2 - mx), w3 = __expf(lg3 - mx);
        float inv = 1.f / (w0 + w1 + w2 + w3);
        w0 *= inv; w1 *= inv; w2 *= inv; w3 *= inv;

        ushort* urow = &s0[p * LDA + h * 64];   // overwrite own slice only
        #pragma unroll
        for (int c8 = 0; c8 < 8; ++c8) {
            bf16x8 t0 = *(const bf16x8*)&trow[c8 * 8];
            bf16x8 t1 = *(const bf16x8*)&trow[64 + c8 * 8];
            bf16x8 t2 = *(const bf16x8*)&trow[128 + c8 * 8];
            bf16x8 t3 = *(const bf16x8*)&trow[192 + c8 * 8];
            bf16x8 uv;
            #pragma unroll
            for (int e = 0; e < 8; ++e) {
                float u = w0 * bf2f((ushort)t0[e]) + w1 * bf2f((ushort)t1[e])
                        + w2 * bf2f((ushort)t2[e]) + w3 * bf2f((ushort)t3[e]);
                uv[e] = (short)f2bf(u);
            }
            *(bf16x8*)&urow[c8 * 8] = uv;
        }
    }
    __syncthreads();

    // ---- GEMM2: OUT[64][128] = U[64][256] @ G[256][128]
    //      wave wv owns cols [wv*32, wv*32+32)
    f32x4 acc2[4][2];
    #pragma unroll
    for (int mt = 0; mt < 4; ++mt)
        #pragma unroll
        for (int nt = 0; nt < 2; ++nt)
            acc2[mt][nt] = (f32x4){0.f, 0.f, 0.f, 0.f};

    #pragma unroll
    for (int kt = 0; kt < 8; ++kt) {
        bf16x8 af[4], bfr[2];
        #pragma unroll
        for (int mt = 0; mt < 4; ++mt)
            af[mt] = *(const bf16x8*)&s0[(mt * 16 + lr) * LDA + kt * 32 + lk];
        #pragma unroll
        for (int nt = 0; nt < 2; ++nt) {
            int co = wv * 32 + nt * 16 + lr;
            bfr[nt] = *(const bf16x8*)(Gt + co * HC + kt * 32 + lk);
        }
        #pragma unroll
        for (int mt = 0; mt < 4; ++mt)
            #pragma unroll
            for (int nt = 0; nt < 2; ++nt)
                acc2[mt][nt] = __builtin_amdgcn_mfma_f32_16x16x32_bf16(
                    af[mt], bfr[nt], acc2[mt][nt], 0, 0, 0);
    }

    // ---- epilogue: add bias, store fp32 --------------------------------
    #pragma unroll
    for (int nt = 0; nt < 2; ++nt) {
        int co = wv * 32 + nt * 16 + lr;
        float bias = bo[co];
        #pragma unroll
        for (int mt = 0; mt < 4; ++mt) {
            int row = mt * 16 + ((lane >> 4) << 2);
            #pragma unroll
            for (int r = 0; r < 4; ++r)
                out[(size_t)(pg0 + row + r) * CIN + co] = acc2[mt][nt][r] + bias;
        }
    }
}

extern "C" void kernel_launch(void* const* d_in, const int* in_sizes, int n_in,
                              void* d_out, int out_size, void* d_ws, size_t ws_size,
                              hipStream_t stream) {
    const float* z2d = (const float*)d_in[0];
    const float* t2d = (const float*)d_in[1];
    const float* Wq  = (const float*)d_in[2];
    const float* Wk  = (const float*)d_in[3];
    const float* Wv  = (const float*)d_in[4];
    const float* Wo  = (const float*)d_in[5];
    const float* bo  = (const float*)d_in[6];

    // workspace: Mt (256x128 bf16) then Gt (128x256 bf16) = 128 KiB total
    ushort* Mt = (ushort*)d_ws;
    ushort* Gt = Mt + HC * CIN;

    precompute_mg<<<(2 * HC * CIN) / 256, 256, 0, stream>>>(Wq, Wk, Wv, Wo, Mt, Gt);
    tpa_fused<<<P_ / TP, 256, 0, stream>>>(z2d, t2d, Mt, Gt, bo, (float*)d_out);
}